// Round 1
// baseline (630.515 us; speedup 1.0000x reference)
//
#include <hip/hip_runtime.h>

// Problem constants (shapes are fixed by the reference; lane mappings assume T=4, F=64).
#define T_DIM 4
#define F_DIM 64

__global__ void zero_kernel(float* __restrict__ p, int n) {
  int i = blockIdx.x * blockDim.x + threadIdx.x;
  if (i < n) p[i] = 0.0f;
}

__global__ void hist_kernel(const int* __restrict__ dst, int* __restrict__ indeg, int E) {
  int e = blockIdx.x * blockDim.x + threadIdx.x;
  if (e < E) atomicAdd(&indeg[dst[e]], 1);
}

// Single-block exclusive scan over N elements (wave shfl scan + serial wave-sum combine).
__global__ __launch_bounds__(1024) void scan_kernel(const int* __restrict__ indeg,
                                                    int* __restrict__ offsets,
                                                    int* __restrict__ cursor, int n) {
  __shared__ int wsum[16];
  __shared__ int chunk_total;
  __shared__ int carry_s;
  const int tid = threadIdx.x;
  const int lane = tid & 63;
  const int wid = tid >> 6;
  if (tid == 0) carry_s = 0;
  __syncthreads();
  for (int base = 0; base < n; base += 1024) {
    int i = base + tid;
    int v = (i < n) ? indeg[i] : 0;
    int s = v;
    #pragma unroll
    for (int off = 1; off < 64; off <<= 1) {
      int t = __shfl_up(s, off, 64);
      if (lane >= off) s += t;
    }
    if (lane == 63) wsum[wid] = s;
    __syncthreads();
    if (tid == 0) {
      int acc = 0;
      #pragma unroll
      for (int w = 0; w < 16; ++w) { int t = wsum[w]; wsum[w] = acc; acc += t; }
      chunk_total = acc;
    }
    __syncthreads();
    int excl = s - v + wsum[wid] + carry_s;
    if (i < n) { offsets[i] = excl; cursor[i] = excl; }
    __syncthreads();
    if (tid == 0) carry_s += chunk_total;
    __syncthreads();
  }
  if (tid == 0) offsets[n] = carry_s;
}

// Scatter edges into CSR slots; pre-pack src id and the 4 per-time weights per edge.
__global__ void fill_kernel(const int* __restrict__ src, const int* __restrict__ dst,
                            const float* __restrict__ ew, int* __restrict__ cursor,
                            int* __restrict__ csr_src, float4* __restrict__ csr_w, int E) {
  int e = blockIdx.x * blockDim.x + threadIdx.x;
  if (e >= E) return;
  int d = dst[e];
  int pos = atomicAdd(&cursor[d], 1);
  csr_src[pos] = src[e];
  float4 w;
  w.x = ew[0 * E + e];
  w.y = ew[1 * E + e];
  w.z = ew[2 * E + e];
  w.w = ew[3 * E + e];
  csr_w[pos] = w;
}

// One wave per node. lane -> (t = lane>>4, f4 = (lane&15)*4); float4 per lane covers (T*F)=256.
// LAYER 0: h_in = node_features, add pe[identities[t]] on the fly.
// LAYER 1: h_in = y0, apply relu(y*scale+shift) (fused BN from layer 0) on the fly.
template <int LAYER>
__global__ __launch_bounds__(256) void aggregate_kernel(
    const float* __restrict__ h_in, const int* __restrict__ offsets,
    const int* __restrict__ csr_src, const float* __restrict__ csr_w,
    const float* __restrict__ pe, const int* __restrict__ identities,
    const float* __restrict__ scale, const float* __restrict__ shiftv,
    float* __restrict__ agg, int n_nodes) {
  const int lane = threadIdx.x & 63;
  const int wid = threadIdx.x >> 6;
  const int v = blockIdx.x * 4 + wid;
  if (v >= n_nodes) return;
  const int t = lane >> 4;
  const int f4 = (lane & 15) << 2;
  const int elem = lane << 2;  // == t*64 + f4

  float4 addv = make_float4(0.f, 0.f, 0.f, 0.f);
  float4 sc = make_float4(0.f, 0.f, 0.f, 0.f);
  float4 sh = make_float4(0.f, 0.f, 0.f, 0.f);
  if (LAYER == 0) {
    addv = *reinterpret_cast<const float4*>(&pe[identities[t] * F_DIM + f4]);
  } else {
    sc = *reinterpret_cast<const float4*>(&scale[f4]);
    sh = *reinterpret_cast<const float4*>(&shiftv[f4]);
  }

  float4 acc = make_float4(0.f, 0.f, 0.f, 0.f);
  const int beg = offsets[v];
  const int end = offsets[v + 1];
  for (int i = beg; i < end; ++i) {
    const int s = csr_src[i];
    const float w = csr_w[i * 4 + t];
    float4 x = *reinterpret_cast<const float4*>(&h_in[(size_t)s * (T_DIM * F_DIM) + elem]);
    if (LAYER == 0) {
      x.x += addv.x; x.y += addv.y; x.z += addv.z; x.w += addv.w;
    } else {
      x.x = fmaxf(0.f, fmaf(x.x, sc.x, sh.x));
      x.y = fmaxf(0.f, fmaf(x.y, sc.y, sh.y));
      x.z = fmaxf(0.f, fmaf(x.z, sc.z, sh.z));
      x.w = fmaxf(0.f, fmaf(x.w, sc.w, sh.w));
    }
    acc.x = fmaf(w, x.x, acc.x);
    acc.y = fmaf(w, x.y, acc.y);
    acc.z = fmaf(w, x.z, acc.z);
    acc.w = fmaf(w, x.w, acc.w);
  }
  *reinterpret_cast<float4*>(&agg[(size_t)v * (T_DIM * F_DIM) + elem]) = acc;
}

// y[r,f] = sum_k agg[r,k]*W[k,f]; W column in registers; fused per-channel sum/sumsq (BN stats).
// LAYER 1 additionally accumulates colsum[t,f] = sum_v agg[v,t,f] (t == sub, since r = c*4+sub).
template <int LAYER>
__global__ __launch_bounds__(256) void matmul_stats_kernel(
    const float* __restrict__ agg, const float* __restrict__ W,
    float* __restrict__ y, float* __restrict__ stats, float* __restrict__ colsum, int R) {
  const int tid = threadIdx.x;
  const int f = tid & 63;
  const int sub = tid >> 6;  // 0..3: row-within-chunk == time index t
  float wcol[64];
  #pragma unroll
  for (int k = 0; k < 64; ++k) wcol[k] = W[k * 64 + f];

  float sum = 0.f, sumsq = 0.f, cs = 0.f;
  const int chunks = R >> 2;
  const int iters = (chunks + gridDim.x - 1) / gridDim.x;
  for (int it = 0; it < iters; ++it) {
    const int c = blockIdx.x + it * gridDim.x;
    if (c < chunks) {
      const int r = (c << 2) + sub;
      const float4* row4 = reinterpret_cast<const float4*>(agg + (size_t)r * 64);
      float acc = 0.f;
      #pragma unroll
      for (int k4 = 0; k4 < 16; ++k4) {
        float4 rv = row4[k4];
        acc = fmaf(rv.x, wcol[k4 * 4 + 0], acc);
        acc = fmaf(rv.y, wcol[k4 * 4 + 1], acc);
        acc = fmaf(rv.z, wcol[k4 * 4 + 2], acc);
        acc = fmaf(rv.w, wcol[k4 * 4 + 3], acc);
      }
      y[(size_t)r * 64 + f] = acc;
      sum += acc;
      sumsq += acc * acc;
      if (LAYER == 1) cs += agg[(size_t)r * 64 + f];
    }
  }
  __shared__ float red[2][256];
  red[0][tid] = sum;
  red[1][tid] = sumsq;
  __syncthreads();
  if (sub == 0) {
    float s0 = red[0][f] + red[0][64 + f] + red[0][128 + f] + red[0][192 + f];
    float s1 = red[1][f] + red[1][64 + f] + red[1][128 + f] + red[1][192 + f];
    atomicAdd(&stats[f], s0);
    atomicAdd(&stats[64 + f], s1);
  }
  if (LAYER == 1) atomicAdd(&colsum[tid], cs);  // tid == sub*64+f == t*64+f
}

__global__ void bn_params_kernel(const float* __restrict__ stats, const float* __restrict__ g,
                                 const float* __restrict__ b, float* __restrict__ scale,
                                 float* __restrict__ shiftv, float inv_count) {
  int f = threadIdx.x;  // 64
  float mean = stats[f] * inv_count;
  float var = stats[64 + f] * inv_count - mean * mean;
  float sc = g[f] * rsqrtf(var + 1e-5f);
  scale[f] = sc;
  shiftv[f] = fmaf(-mean, sc, b[f]);
}

__global__ void readout_kernel(const float* __restrict__ colsum, const float* __restrict__ W,
                               float* __restrict__ out, float invN) {
  int tid = threadIdx.x;  // 256 = t*64+f
  int t = tid >> 6, f = tid & 63;
  float acc = 0.f;
  #pragma unroll
  for (int k = 0; k < 64; ++k) acc = fmaf(colsum[t * 64 + k] * invN, W[k * 64 + f], acc);
  out[tid] = acc;
}

__global__ void bn_relu_kernel(float* __restrict__ y, const float* __restrict__ scale,
                               const float* __restrict__ shiftv, int nvec4) {
  int i = blockIdx.x * blockDim.x + threadIdx.x;
  const int stride = gridDim.x * blockDim.x;
  for (; i < nvec4; i += stride) {
    float4 v = reinterpret_cast<float4*>(y)[i];
    int f4 = (i << 2) & 63;
    float4 sc = *reinterpret_cast<const float4*>(&scale[f4]);
    float4 sh = *reinterpret_cast<const float4*>(&shiftv[f4]);
    v.x = fmaxf(0.f, fmaf(v.x, sc.x, sh.x));
    v.y = fmaxf(0.f, fmaf(v.y, sc.y, sh.y));
    v.z = fmaxf(0.f, fmaf(v.z, sc.z, sh.z));
    v.w = fmaxf(0.f, fmaf(v.w, sc.w, sh.w));
    reinterpret_cast<float4*>(y)[i] = v;
  }
}

extern "C" void kernel_launch(void* const* d_in, const int* in_sizes, int n_in,
                              void* d_out, int out_size, void* d_ws, size_t ws_size,
                              hipStream_t stream) {
  const float* node_features = (const float*)d_in[0];
  const float* edges_weight  = (const float*)d_in[1];
  const int*   identities    = (const int*)d_in[2];
  const int*   edge_src      = (const int*)d_in[3];
  const int*   edge_dst      = (const int*)d_in[4];
  const float* pe            = (const float*)d_in[5];
  const float* W0            = (const float*)d_in[6];
  const float* W1            = (const float*)d_in[7];
  const float* g0            = (const float*)d_in[8];
  const float* b0            = (const float*)d_in[9];
  const float* g1            = (const float*)d_in[10];
  const float* b1            = (const float*)d_in[11];

  const int T = in_sizes[2];            // 4
  const int E = in_sizes[3];            // 800000
  const int F = in_sizes[8];            // 64
  const int N = in_sizes[0] / (T * F);  // 50000
  const int R = N * T;                  // 200000 rows of F

  float* out = (float*)d_out;
  float* out_h = out;                               // (N,T,F)
  float* out_readout = out + (size_t)N * T * F;     // (T,F)

  // ---- workspace layout (256B-aligned regions) ----
  char* ws = (char*)d_ws;
  size_t off = 0;
  auto alloc = [&](size_t bytes) -> void* {
    off = (off + 255) & ~(size_t)255;
    void* p = ws + off;
    off += bytes;
    return p;
  };
  float* stats0  = (float*)alloc(128 * sizeof(float));
  float* stats1  = (float*)alloc(128 * sizeof(float));
  float* colsum  = (float*)alloc(256 * sizeof(float));
  int*   indeg   = (int*)alloc((size_t)N * sizeof(int));
  // everything above must be zeroed each call:
  const int zero_n = (int)(((char*)indeg + (size_t)N * sizeof(int) - (char*)stats0) / 4);
  int*    offsets = (int*)alloc(((size_t)N + 1) * sizeof(int));
  int*    cursor  = (int*)alloc((size_t)N * sizeof(int));
  int*    csr_src = (int*)alloc((size_t)E * sizeof(int));
  float4* csr_w   = (float4*)alloc((size_t)E * sizeof(float4));
  float*  agg     = (float*)alloc((size_t)R * F * sizeof(float));
  float*  scale0  = (float*)alloc(64 * sizeof(float));
  float*  shift0  = (float*)alloc(64 * sizeof(float));
  float*  scale1  = (float*)alloc(64 * sizeof(float));
  float*  shift1  = (float*)alloc(64 * sizeof(float));
  (void)ws_size;

  // ---- CSR build (dst-sorted adjacency, rebuilt every call for determinism) ----
  hipLaunchKernelGGL(zero_kernel, dim3((zero_n + 255) / 256), dim3(256), 0, stream, stats0, zero_n);
  hipLaunchKernelGGL(hist_kernel, dim3((E + 255) / 256), dim3(256), 0, stream, edge_dst, indeg, E);
  hipLaunchKernelGGL(scan_kernel, dim3(1), dim3(1024), 0, stream, indeg, offsets, cursor, N);
  hipLaunchKernelGGL(fill_kernel, dim3((E + 255) / 256), dim3(256), 0, stream,
                     edge_src, edge_dst, edges_weight, cursor, csr_src, csr_w, E);

  const int agg_blocks = (N + 3) / 4;

  // ---- layer 0 ----
  hipLaunchKernelGGL((aggregate_kernel<0>), dim3(agg_blocks), dim3(256), 0, stream,
                     node_features, offsets, csr_src, (const float*)csr_w,
                     pe, identities, nullptr, nullptr, agg, N);
  hipLaunchKernelGGL((matmul_stats_kernel<0>), dim3(1024), dim3(256), 0, stream,
                     agg, W0, out_h /*y0*/, stats0, nullptr, R);
  hipLaunchKernelGGL(bn_params_kernel, dim3(1), dim3(64), 0, stream,
                     stats0, g0, b0, scale0, shift0, 1.0f / (float)R);

  // ---- layer 1 (BN0+ReLU fused into the gather) ----
  hipLaunchKernelGGL((aggregate_kernel<1>), dim3(agg_blocks), dim3(256), 0, stream,
                     out_h /*y0*/, offsets, csr_src, (const float*)csr_w,
                     nullptr, nullptr, scale0, shift0, agg, N);
  hipLaunchKernelGGL((matmul_stats_kernel<1>), dim3(1024), dim3(256), 0, stream,
                     agg, W1, out_h /*y1*/, stats1, colsum, R);
  hipLaunchKernelGGL(bn_params_kernel, dim3(1), dim3(64), 0, stream,
                     stats1, g1, b1, scale1, shift1, 1.0f / (float)R);

  // ---- readout = (colsum/N) @ W1 ----
  hipLaunchKernelGGL(readout_kernel, dim3(1), dim3(256), 0, stream,
                     colsum, W1, out_readout, 1.0f / (float)N);

  // ---- final BN1 + ReLU in place on d_out h-region ----
  hipLaunchKernelGGL(bn_relu_kernel, dim3(2048), dim3(256), 0, stream,
                     out_h, scale1, shift1, (R * F) >> 2);
}

// Round 2
// 414.326 us; speedup vs baseline: 1.5218x; 1.5218x over previous
//
#include <hip/hip_runtime.h>

// Shapes fixed by the reference: T=4, F=64, row = T*F = 256 elems.
#define TF 256

// ---------- bf16 helpers (fp32 <-> bf16, RNE) ----------
__device__ inline unsigned short f2bf(float x) {
  unsigned u = __float_as_uint(x);
  u += 0x7fffu + ((u >> 16) & 1u);
  return (unsigned short)(u >> 16);
}
__device__ inline unsigned pack2(unsigned short lo, unsigned short hi) {
  return (unsigned)lo | ((unsigned)hi << 16);
}
__device__ inline float bflo(unsigned u) { return __uint_as_float(u << 16); }
__device__ inline float bfhi(unsigned u) { return __uint_as_float(u & 0xffff0000u); }

__global__ void zero_kernel(float* __restrict__ p, int n) {
  int i = blockIdx.x * blockDim.x + threadIdx.x;
  if (i < n) p[i] = 0.0f;
}

__global__ void hist_kernel(const int* __restrict__ dst, int* __restrict__ indeg, int E) {
  int e = blockIdx.x * blockDim.x + threadIdx.x;
  if (e < E) atomicAdd(&indeg[dst[e]], 1);
}

// ---------- hierarchical scan: part1 = per-block reduce ----------
__global__ __launch_bounds__(1024) void scan_part1(const int* __restrict__ indeg,
                                                   int* __restrict__ partials, int n) {
  __shared__ int wsum[16];
  const int tid = threadIdx.x;
  const int lane = tid & 63;
  const int wid = tid >> 6;
  int i = blockIdx.x * 1024 + tid;
  int s = (i < n) ? indeg[i] : 0;
  #pragma unroll
  for (int o = 1; o < 64; o <<= 1) s += __shfl_xor(s, o, 64);
  if (lane == 0) wsum[wid] = s;
  __syncthreads();
  if (tid == 0) {
    int acc = 0;
    #pragma unroll
    for (int w = 0; w < 16; ++w) acc += wsum[w];
    partials[blockIdx.x] = acc;
  }
}

// part2: exclusive scan of <=64 block partials (single wave)
__global__ __launch_bounds__(64) void scan_part2(const int* __restrict__ partials,
                                                 int* __restrict__ base,
                                                 int* __restrict__ offsets, int nb, int n) {
  const int i = threadIdx.x;
  int v = (i < nb) ? partials[i] : 0;
  int s = v;
  #pragma unroll
  for (int o = 1; o < 64; o <<= 1) {
    int t = __shfl_up(s, o, 64);
    if (i >= o) s += t;
  }
  if (i < nb) base[i] = s - v;
  if (i == nb - 1) offsets[n] = s;  // total == E
}

// part3: block-local exclusive scan + carry; writes offsets and cursor
__global__ __launch_bounds__(1024) void scan_part3(const int* __restrict__ indeg,
                                                   const int* __restrict__ base,
                                                   int* __restrict__ offsets,
                                                   int* __restrict__ cursor, int n) {
  __shared__ int wsum[16];
  const int tid = threadIdx.x;
  const int lane = tid & 63;
  const int wid = tid >> 6;
  int i = blockIdx.x * 1024 + tid;
  int v = (i < n) ? indeg[i] : 0;
  int s = v;
  #pragma unroll
  for (int o = 1; o < 64; o <<= 1) {
    int t = __shfl_up(s, o, 64);
    if (lane >= o) s += t;
  }
  if (lane == 63) wsum[wid] = s;
  __syncthreads();
  if (tid == 0) {
    int acc = 0;
    #pragma unroll
    for (int w = 0; w < 16; ++w) { int t = wsum[w]; wsum[w] = acc; acc += t; }
  }
  __syncthreads();
  int excl = s - v + wsum[wid] + base[blockIdx.x];
  if (i < n) { offsets[i] = excl; cursor[i] = excl; }
}

// scatter edges into CSR slots; pre-pack src id + 4 per-time weights
__global__ void fill_kernel(const int* __restrict__ src, const int* __restrict__ dst,
                            const float* __restrict__ ew, int* __restrict__ cursor,
                            int* __restrict__ csr_src, float4* __restrict__ csr_w, int E) {
  int e = blockIdx.x * blockDim.x + threadIdx.x;
  if (e >= E) return;
  int d = dst[e];
  int pos = atomicAdd(&cursor[d], 1);
  csr_src[pos] = src[e];
  float4 w;
  w.x = ew[0 * E + e];
  w.y = ew[1 * E + e];
  w.z = ew[2 * E + e];
  w.w = ew[3 * E + e];
  csr_w[pos] = w;
}

// h0_bf16 = bf16(node_features + pe[identities[t]]); 4 elems/thread
__global__ void prep_kernel(const float* __restrict__ x, const float* __restrict__ pe,
                            const int* __restrict__ ids, uint2* __restrict__ h0, int n4) {
  int i = blockIdx.x * blockDim.x + threadIdx.x;
  const int stride = gridDim.x * blockDim.x;
  for (; i < n4; i += stride) {
    int e0 = (i << 2) & (TF - 1);
    int t = e0 >> 6;
    int f4 = e0 & 63;
    float4 v = reinterpret_cast<const float4*>(x)[i];
    float4 p = *reinterpret_cast<const float4*>(&pe[ids[t] * 64 + f4]);
    uint2 o;
    o.x = pack2(f2bf(v.x + p.x), f2bf(v.y + p.y));
    o.y = pack2(f2bf(v.z + p.z), f2bf(v.w + p.w));
    h0[i] = o;
  }
}

// One wave per node; lane covers elems [lane*4, lane*4+4) of the 256-wide row (uint2 of bf16).
// LAYER 1 applies relu(y*scale+shift) (layer-0 BN) to gathered values on the fly.
template <int LAYER>
__global__ __launch_bounds__(256) void aggregate_kernel(
    const uint2* __restrict__ h_in, const int* __restrict__ offsets,
    const int* __restrict__ csr_src, const float* __restrict__ csr_w,
    const float* __restrict__ scale, const float* __restrict__ shiftv,
    uint2* __restrict__ agg, int n_nodes) {
  const int lane = threadIdx.x & 63;
  const int wid = threadIdx.x >> 6;
  const int v = blockIdx.x * 4 + wid;
  if (v >= n_nodes) return;
  const int t = lane >> 4;
  const int f4 = (lane & 15) << 2;

  float4 sc = make_float4(0.f, 0.f, 0.f, 0.f);
  float4 sh = make_float4(0.f, 0.f, 0.f, 0.f);
  if (LAYER == 1) {
    sc = *reinterpret_cast<const float4*>(&scale[f4]);
    sh = *reinterpret_cast<const float4*>(&shiftv[f4]);
  }

  float a0 = 0.f, a1 = 0.f, a2 = 0.f, a3 = 0.f;

  auto body = [&](uint2 q, float w) {
    float x0 = bflo(q.x), x1 = bfhi(q.x), x2 = bflo(q.y), x3 = bfhi(q.y);
    if (LAYER == 1) {
      x0 = fmaxf(0.f, fmaf(x0, sc.x, sh.x));
      x1 = fmaxf(0.f, fmaf(x1, sc.y, sh.y));
      x2 = fmaxf(0.f, fmaf(x2, sc.z, sh.z));
      x3 = fmaxf(0.f, fmaf(x3, sc.w, sh.w));
    }
    a0 = fmaf(w, x0, a0);
    a1 = fmaf(w, x1, a1);
    a2 = fmaf(w, x2, a2);
    a3 = fmaf(w, x3, a3);
  };

  const int beg = offsets[v];
  const int end = offsets[v + 1];
  int i = beg;
  for (; i + 2 <= end; i += 2) {  // 2 independent row loads in flight
    const int s0 = csr_src[i];
    const int s1 = csr_src[i + 1];
    const float w0 = csr_w[i * 4 + t];
    const float w1 = csr_w[i * 4 + 4 + t];
    const uint2 q0 = h_in[(size_t)s0 * 64 + lane];
    const uint2 q1 = h_in[(size_t)s1 * 64 + lane];
    body(q0, w0);
    body(q1, w1);
  }
  if (i < end) {
    const int s0 = csr_src[i];
    const float w0 = csr_w[i * 4 + t];
    body(h_in[(size_t)s0 * 64 + lane], w0);
  }

  uint2 o;
  o.x = pack2(f2bf(a0), f2bf(a1));
  o.y = pack2(f2bf(a2), f2bf(a3));
  agg[(size_t)v * 64 + lane] = o;
}

// y[r,f] = sum_k agg_bf16[r,k]*W[k,f]; W column in 64 VGPRs; fused BN stats (fp32 acc).
// LAYER 0 stores y as bf16 (feeds layer-1 gather); LAYER 1 stores fp32 to d_out + colsum.
template <int LAYER>
__global__ __launch_bounds__(256) void matmul_stats_kernel(
    const unsigned short* __restrict__ aggb, const float* __restrict__ W,
    unsigned short* __restrict__ y_bf, float* __restrict__ y_f32,
    float* __restrict__ stats, float* __restrict__ colsum, int R) {
  const int tid = threadIdx.x;
  const int f = tid & 63;
  const int sub = tid >> 6;  // row-within-chunk == time index t
  float wcol[64];
  #pragma unroll
  for (int k = 0; k < 64; ++k) wcol[k] = W[k * 64 + f];

  float sum = 0.f, sumsq = 0.f, cs = 0.f;
  const int chunks = R >> 2;
  for (int c = blockIdx.x; c < chunks; c += gridDim.x) {
    const int r = (c << 2) + sub;
    const uint4* rowq = reinterpret_cast<const uint4*>(aggb + (size_t)r * 64);
    float acc = 0.f;
    #pragma unroll
    for (int q = 0; q < 8; ++q) {
      uint4 u = rowq[q];
      const int k = q * 8;
      acc = fmaf(bflo(u.x), wcol[k + 0], acc);
      acc = fmaf(bfhi(u.x), wcol[k + 1], acc);
      acc = fmaf(bflo(u.y), wcol[k + 2], acc);
      acc = fmaf(bfhi(u.y), wcol[k + 3], acc);
      acc = fmaf(bflo(u.z), wcol[k + 4], acc);
      acc = fmaf(bfhi(u.z), wcol[k + 5], acc);
      acc = fmaf(bflo(u.w), wcol[k + 6], acc);
      acc = fmaf(bfhi(u.w), wcol[k + 7], acc);
    }
    if (LAYER == 0) {
      y_bf[(size_t)r * 64 + f] = f2bf(acc);
    } else {
      y_f32[(size_t)r * 64 + f] = acc;
      cs += __uint_as_float(((unsigned)aggb[(size_t)r * 64 + f]) << 16);
    }
    sum += acc;
    sumsq += acc * acc;
  }
  __shared__ float red[2][256];
  red[0][tid] = sum;
  red[1][tid] = sumsq;
  __syncthreads();
  if (sub == 0) {
    float s0 = red[0][f] + red[0][64 + f] + red[0][128 + f] + red[0][192 + f];
    float s1 = red[1][f] + red[1][64 + f] + red[1][128 + f] + red[1][192 + f];
    atomicAdd(&stats[f], s0);
    atomicAdd(&stats[64 + f], s1);
  }
  if (LAYER == 1) atomicAdd(&colsum[tid], cs);  // tid == t*64+f
}

__global__ void bn_params_kernel(const float* __restrict__ stats, const float* __restrict__ g,
                                 const float* __restrict__ b, float* __restrict__ scale,
                                 float* __restrict__ shiftv, float inv_count) {
  int f = threadIdx.x;  // 64
  float mean = stats[f] * inv_count;
  float var = stats[64 + f] * inv_count - mean * mean;
  float sc = g[f] * rsqrtf(var + 1e-5f);
  scale[f] = sc;
  shiftv[f] = fmaf(-mean, sc, b[f]);
}

// fused: layer-1 BN params (threads 0..63) + readout = (colsum/N) @ W1 (all 256)
__global__ __launch_bounds__(256) void finalize_kernel(
    const float* __restrict__ stats, const float* __restrict__ g, const float* __restrict__ b,
    float* __restrict__ scale, float* __restrict__ shiftv, float inv_count,
    const float* __restrict__ colsum, const float* __restrict__ W,
    float* __restrict__ out_readout, float invN) {
  int tid = threadIdx.x;
  if (tid < 64) {
    float mean = stats[tid] * inv_count;
    float var = stats[64 + tid] * inv_count - mean * mean;
    float sc = g[tid] * rsqrtf(var + 1e-5f);
    scale[tid] = sc;
    shiftv[tid] = fmaf(-mean, sc, b[tid]);
  }
  int t = tid >> 6, f = tid & 63;
  float acc = 0.f;
  #pragma unroll
  for (int k = 0; k < 64; ++k) acc = fmaf(colsum[t * 64 + k] * invN, W[k * 64 + f], acc);
  out_readout[tid] = acc;
}

__global__ void bn_relu_kernel(float* __restrict__ y, const float* __restrict__ scale,
                               const float* __restrict__ shiftv, int nvec4) {
  int i = blockIdx.x * blockDim.x + threadIdx.x;
  const int stride = gridDim.x * blockDim.x;
  for (; i < nvec4; i += stride) {
    float4 v = reinterpret_cast<float4*>(y)[i];
    int f4 = (i << 2) & 63;
    float4 sc = *reinterpret_cast<const float4*>(&scale[f4]);
    float4 sh = *reinterpret_cast<const float4*>(&shiftv[f4]);
    v.x = fmaxf(0.f, fmaf(v.x, sc.x, sh.x));
    v.y = fmaxf(0.f, fmaf(v.y, sc.y, sh.y));
    v.z = fmaxf(0.f, fmaf(v.z, sc.z, sh.z));
    v.w = fmaxf(0.f, fmaf(v.w, sc.w, sh.w));
    reinterpret_cast<float4*>(y)[i] = v;
  }
}

extern "C" void kernel_launch(void* const* d_in, const int* in_sizes, int n_in,
                              void* d_out, int out_size, void* d_ws, size_t ws_size,
                              hipStream_t stream) {
  const float* node_features = (const float*)d_in[0];
  const float* edges_weight  = (const float*)d_in[1];
  const int*   identities    = (const int*)d_in[2];
  const int*   edge_src      = (const int*)d_in[3];
  const int*   edge_dst      = (const int*)d_in[4];
  const float* W0            = (const float*)d_in[6];
  const float* W1            = (const float*)d_in[7];
  const float* g0            = (const float*)d_in[8];
  const float* b0            = (const float*)d_in[9];
  const float* g1            = (const float*)d_in[10];
  const float* b1            = (const float*)d_in[11];
  const float* pe            = (const float*)d_in[5];

  const int T = in_sizes[2];            // 4
  const int E = in_sizes[3];            // 800000
  const int F = in_sizes[8];            // 64
  const int N = in_sizes[0] / (T * F);  // 50000
  const int R = N * T;                  // 200000

  float* out = (float*)d_out;
  float* out_h = out;                            // (N,T,F) fp32
  float* out_readout = out + (size_t)N * T * F;  // (T,F)

  // ---- workspace layout ----
  char* ws = (char*)d_ws;
  size_t off = 0;
  auto alloc = [&](size_t bytes) -> void* {
    off = (off + 255) & ~(size_t)255;
    void* p = ws + off;
    off += bytes;
    return p;
  };
  float* stats0  = (float*)alloc(128 * sizeof(float));
  float* stats1  = (float*)alloc(128 * sizeof(float));
  float* colsum  = (float*)alloc(256 * sizeof(float));
  int*   indeg   = (int*)alloc((size_t)N * sizeof(int));
  const int zero_n = (int)(((char*)indeg + (size_t)N * sizeof(int) - (char*)stats0) / 4);
  int*    partials = (int*)alloc(64 * sizeof(int));
  int*    base_    = (int*)alloc(64 * sizeof(int));
  int*    offsets  = (int*)alloc(((size_t)N + 1) * sizeof(int));
  int*    cursor   = (int*)alloc((size_t)N * sizeof(int));
  int*    csr_src  = (int*)alloc((size_t)E * sizeof(int));
  float4* csr_w    = (float4*)alloc((size_t)E * sizeof(float4));
  unsigned short* h0b  = (unsigned short*)alloc((size_t)N * TF * 2);  // reused as y0b
  unsigned short* aggb = (unsigned short*)alloc((size_t)N * TF * 2);
  float*  scale0 = (float*)alloc(64 * sizeof(float));
  float*  shift0 = (float*)alloc(64 * sizeof(float));
  float*  scale1 = (float*)alloc(64 * sizeof(float));
  float*  shift1 = (float*)alloc(64 * sizeof(float));
  (void)ws_size;

  const int nb = (N + 1023) / 1024;  // <=64 (N<=65536)

  // ---- CSR build ----
  hipLaunchKernelGGL(zero_kernel, dim3((zero_n + 255) / 256), dim3(256), 0, stream, stats0, zero_n);
  hipLaunchKernelGGL(hist_kernel, dim3((E + 255) / 256), dim3(256), 0, stream, edge_dst, indeg, E);
  hipLaunchKernelGGL(scan_part1, dim3(nb), dim3(1024), 0, stream, indeg, partials, N);
  hipLaunchKernelGGL(scan_part2, dim3(1), dim3(64), 0, stream, partials, base_, offsets, nb, N);
  hipLaunchKernelGGL(scan_part3, dim3(nb), dim3(1024), 0, stream, indeg, base_, offsets, cursor, N);
  hipLaunchKernelGGL(fill_kernel, dim3((E + 255) / 256), dim3(256), 0, stream,
                     edge_src, edge_dst, edges_weight, cursor, csr_src, csr_w, E);

  // ---- prep: h0 = bf16(x + pe[ids]) ----
  hipLaunchKernelGGL(prep_kernel, dim3(2048), dim3(256), 0, stream,
                     node_features, pe, identities, (uint2*)h0b, (N * TF) / 4);

  const int agg_blocks = (N + 3) / 4;

  // ---- layer 0 ----
  hipLaunchKernelGGL((aggregate_kernel<0>), dim3(agg_blocks), dim3(256), 0, stream,
                     (const uint2*)h0b, offsets, csr_src, (const float*)csr_w,
                     nullptr, nullptr, (uint2*)aggb, N);
  hipLaunchKernelGGL((matmul_stats_kernel<0>), dim3(1024), dim3(256), 0, stream,
                     aggb, W0, h0b /*y0b: reuse h0 buffer*/, nullptr, stats0, nullptr, R);
  hipLaunchKernelGGL(bn_params_kernel, dim3(1), dim3(64), 0, stream,
                     stats0, g0, b0, scale0, shift0, 1.0f / (float)R);

  // ---- layer 1 (BN0+ReLU fused into gather) ----
  hipLaunchKernelGGL((aggregate_kernel<1>), dim3(agg_blocks), dim3(256), 0, stream,
                     (const uint2*)h0b /*y0b*/, offsets, csr_src, (const float*)csr_w,
                     scale0, shift0, (uint2*)aggb, N);
  hipLaunchKernelGGL((matmul_stats_kernel<1>), dim3(1024), dim3(256), 0, stream,
                     aggb, W1, nullptr, out_h, stats1, colsum, R);

  // ---- layer-1 BN params + readout ----
  hipLaunchKernelGGL(finalize_kernel, dim3(1), dim3(256), 0, stream,
                     stats1, g1, b1, scale1, shift1, 1.0f / (float)R,
                     colsum, W1, out_readout, 1.0f / (float)N);

  // ---- final BN1 + ReLU in place ----
  hipLaunchKernelGGL(bn_relu_kernel, dim3(2048), dim3(256), 0, stream,
                     out_h, scale1, shift1, (R * F) >> 2);
}